// Round 10
// baseline (11594.346 us; speedup 1.0000x reference)
//
#include <hip/hip_runtime.h>
#include <math.h>

#define NDIMX 2941
#define NQ 1200
#define KB 800
#define KP 720
#define KU 1520
#define NC 400
#define NBT 128
#define NRHS 528
#define GRID 512
#define TPB 256
#define PRLD 832

__device__ __forceinline__ int umap(int x){ return (x < 1200) ? x : x - 720; }

__device__ __forceinline__ const float* qrowp(int rr, const float* Yf, const float* Uf,
                                              const float* Up, const float* Yp){
  if (rr < 480) return Yf + (size_t)rr*NDIMX;
  if (rr < 800) return Uf + (size_t)(rr-480)*NDIMX;
  if (rr < 960) return Up + (size_t)(rr-800)*NDIMX;
  return Yp + (size_t)(rr-960)*NDIMX;
}

// ---------------- device-scope grid barrier (round-5 protocol, verified) ----------------
__device__ __forceinline__ void gbar(unsigned* cnt, int& id){
  __syncthreads();
  if (threadIdx.x == 0){
    unsigned* c = cnt + id;
    __hip_atomic_fetch_add(c, 1u, __ATOMIC_RELEASE, __HIP_MEMORY_SCOPE_SYSTEM);
    while (__hip_atomic_load(c, __ATOMIC_RELAXED, __HIP_MEMORY_SCOPE_SYSTEM) < (unsigned)GRID){
      __builtin_amdgcn_s_sleep(8);
    }
    (void)__hip_atomic_load(c, __ATOMIC_ACQUIRE, __HIP_MEMORY_SCOPE_AGENT);
  }
  __syncthreads();
  id++;
}

// XCD-aware bijective tile range (m204); per-x-lane stride = GRID/8
__device__ __forceinline__ void swz(int T, int& t0, int& tend){
  int x = blockIdx.x & 7, y = blockIdx.x >> 3;
  int q = T >> 3, r = T & 7;
  int nx = q + (x < r ? 1 : 0);
  int base = (x < r) ? x*(q+1) : r*(q+1) + (x-r)*q;
  t0 = base + y; tend = base + nx;
}

// ---------------- Gram stage (round-5 verified: f32 acc, f64 store) ----------------
__device__ void st_gram(const float* Yf, const float* Uf, const float* Up, const float* Yp,
                        double* G, double* shd){
  float* At = (float*)shd;          // [32][65]
  float* Bt = At + 32*65;           // [32][65]
  const int ntri = 190;
  int tid = threadIdx.x, tx = tid%16, ty = tid/16;
  int t0, tend; swz(ntri, t0, tend);
  for (int t = t0; t < tend; t += (GRID>>3)){
    int rem = t, ti = 0;
    while (rem >= ti+1){ rem -= ti+1; ++ti; }
    int tj = rem;
    int i0 = ti*64, j0 = tj*64;
    float acc[4][4] = {};
    for (int k0 = 0; k0 < NDIMX; k0 += 32){
      for (int l = tid; l < 2048; l += TPB){
        int r2 = l >> 5, k = l & 31;
        int gr = i0 + r2, gk = k0 + k;
        At[k*65 + r2] = (gr < NQ && gk < NDIMX) ? qrowp(gr,Yf,Uf,Up,Yp)[gk] : 0.f;
      }
      if (ti != tj){
        for (int l = tid; l < 2048; l += TPB){
          int r2 = l >> 5, k = l & 31;
          int gr = j0 + r2, gk = k0 + k;
          Bt[k*65 + r2] = (gr < NQ && gk < NDIMX) ? qrowp(gr,Yf,Uf,Up,Yp)[gk] : 0.f;
        }
      }
      __syncthreads();
      float* Bp = (ti==tj) ? At : Bt;
      #pragma unroll 8
      for (int kk=0; kk<32; ++kk){
        float a0=At[kk*65+ty*4+0],a1=At[kk*65+ty*4+1],a2=At[kk*65+ty*4+2],a3=At[kk*65+ty*4+3];
        float b0=Bp[kk*65+tx*4+0],b1=Bp[kk*65+tx*4+1],b2=Bp[kk*65+tx*4+2],b3=Bp[kk*65+tx*4+3];
        acc[0][0]+=a0*b0; acc[0][1]+=a0*b1; acc[0][2]+=a0*b2; acc[0][3]+=a0*b3;
        acc[1][0]+=a1*b0; acc[1][1]+=a1*b1; acc[1][2]+=a1*b2; acc[1][3]+=a1*b3;
        acc[2][0]+=a2*b0; acc[2][1]+=a2*b1; acc[2][2]+=a2*b2; acc[2][3]+=a2*b3;
        acc[3][0]+=a3*b0; acc[3][1]+=a3*b1; acc[3][2]+=a3*b2; acc[3][3]+=a3*b3;
      }
      __syncthreads();
    }
    for (int i=0;i<4;i++) for (int j=0;j<4;j++){
      int gi = i0 + ty*4 + i, gj = j0 + tx*4 + j;
      if (gi < NQ && gj < NQ){
        double v = (double)acc[i][j];
        G[(size_t)gi*NQ+gj] = v;
        G[(size_t)gj*NQ+gi] = v;
      }
    }
  }
}

// ---------------- fused elementwise assembly (round-5 verified) ----------------
__device__ void st_assemble(const double* G, const float* q, const float* r, double isg,
    const float* yref, const float* uref, const float* u_ini, const float* y_ini,
    double* M11, double* T12, double* R1, double* dM, double* rhs2){
  int tid0 = blockIdx.x*TPB + threadIdx.x, stride = gridDim.x*TPB;
  for (int idx=tid0; idx<KB*KB; idx+=stride){
    int i=idx/KB, j=idx-i*KB;
    double v = G[(size_t)i*NQ+j]*isg;
    if (i==j){ double w=(i<480)?(double)q[i%12]:(double)r[(i-480)%8]; v += 0.5/w; }
    M11[idx]=v;
  }
  for (int idx=tid0; idx<KB*KP; idx+=stride){
    int i=idx/KP, j=idx-i*KP;
    int pc=(j<400)?(800+j):(80+j);
    T12[idx]=G[(size_t)i*NQ+pc]*isg;
  }
  for (int idx=tid0; idx<KU*NC; idx+=stride){
    int i=idx/NC, j=idx-i*NC;
    R1[(size_t)i*NRHS+j]=G[(size_t)umap(i)*NQ+800+j];
  }
  for (int idx=tid0; idx<KB*NBT; idx+=stride){
    int k=idx/NBT, t=idx-k*NBT;
    dM[idx]=(k<480)? 2.0*(double)q[k%12]*(double)yref[(size_t)t*480+k]
                   : 2.0*(double)r[(k-480)%8]*(double)uref[(size_t)t*320+(k-480)];
  }
  for (int idx=tid0; idx<NC*NBT; idx+=stride){
    int j=idx/NBT, t=idx-j*NBT;
    rhs2[idx]= -((j<160)?(double)u_ini[(size_t)t*160+j]:(double)y_ini[(size_t)t*240+(j-160)]);
  }
}

// ---------------- f64 VALU GEMM (round-5 verified inner), swizzled tiles ----------------
template<int TRANSA, int MAPA>
__device__ void dgemm(const double* __restrict__ A, int lda, const double* __restrict__ B, int ldb,
    const double* __restrict__ Cin, int ldcin, double* __restrict__ Cout, int ldc,
    int M, int N, int K, double alpha, double beta, double* shd){
  double* As = shd;          // [16][66]
  double* Bs = shd + 1056;   // [16][66]
  int tid = threadIdx.x, tx = tid%16, ty = tid/16;
  int ntn = (N+63)>>6, ntm = (M+63)>>6;
  int t0, tend; swz(ntm*ntn, t0, tend);
  for (int t = t0; t < tend; t += (GRID>>3)){
    int m0 = (t/ntn)*64, n0 = (t%ntn)*64;
    double acc[4][4] = {};
    double ra[4], rb[4];
    auto loadAB = [&](int k0v){
      #pragma unroll
      for (int s=0;s<4;s++){
        int l = tid + s*TPB;
        if (TRANSA==0){
          int m = l>>4, k = l&15;
          int gm = m0+m, gk = k0v+k;
          double v = 0.0;
          if (gm<M && gk<K){ int row = MAPA ? umap(gm) : gm; v = A[(size_t)row*lda + gk]; }
          ra[s] = v;
        } else {
          int k = l>>6, m = l&63;
          int gm = m0+m, gk = k0v+k;
          double v = 0.0;
          if (gm<M && gk<K){ int row = MAPA ? umap(gk) : gk; v = A[(size_t)row*lda + gm]; }
          ra[s] = v;
        }
        int kb = l>>6, n = l&63;
        int gn = n0+n, gkb = k0v+kb;
        rb[s] = (gn<N && gkb<K) ? B[(size_t)gkb*ldb + gn] : 0.0;
      }
    };
    loadAB(0);
    for (int k0 = 0; k0 < K; k0 += 16){
      __syncthreads();
      #pragma unroll
      for (int s=0;s<4;s++){
        int l = tid + s*TPB;
        if (TRANSA==0){ int m=l>>4, k=l&15; As[k*66+m] = ra[s]; }
        else          { int k=l>>6, m=l&63; As[k*66+m] = ra[s]; }
        int kb=l>>6, n=l&63; Bs[kb*66+n] = rb[s];
      }
      __syncthreads();
      if (k0+16 < K) loadAB(k0+16);
      #pragma unroll
      for (int kk=0; kk<16; ++kk){
        double a0=As[kk*66+ty*4+0], a1=As[kk*66+ty*4+1], a2=As[kk*66+ty*4+2], a3=As[kk*66+ty*4+3];
        double b0=Bs[kk*66+tx*4+0], b1=Bs[kk*66+tx*4+1], b2=Bs[kk*66+tx*4+2], b3=Bs[kk*66+tx*4+3];
        acc[0][0]+=a0*b0; acc[0][1]+=a0*b1; acc[0][2]+=a0*b2; acc[0][3]+=a0*b3;
        acc[1][0]+=a1*b0; acc[1][1]+=a1*b1; acc[1][2]+=a1*b2; acc[1][3]+=a1*b3;
        acc[2][0]+=a2*b0; acc[2][1]+=a2*b1; acc[2][2]+=a2*b2; acc[2][3]+=a2*b3;
        acc[3][0]+=a3*b0; acc[3][1]+=a3*b1; acc[3][2]+=a3*b2; acc[3][3]+=a3*b3;
      }
      __syncthreads();
    }
    for (int i=0;i<4;i++) for (int j=0;j<4;j++){
      int gm = m0 + ty*4 + i, gn = n0 + tx*4 + j;
      if (gm < M && gn < N){
        double v = alpha*acc[i][j];
        if (beta != 0.0) v += beta*Cin[(size_t)gm*ldcin + gn];
        Cout[(size_t)gm*ldc + gn] = v;
      }
    }
  }
}

// ---------------- blocked Gauss-Jordan, 2 phases/panel (round-9 verified) ----------------
__device__ void gj_pivinv(const double* A, int lda, int n, int k0, double* TP, double* shd){
  int bs = n - k0; if (bs > 64) bs = 64;
  double* sm = shd;            // [64][65]
  double* ck = shd + 64*65;
  double* rk = ck + 64;
  int tid = threadIdx.x;
  for (int l = tid; l < bs*bs; l += TPB){
    int i=l/bs, j=l-i*bs;
    sm[i*65+j] = A[(size_t)(k0+i)*lda + k0+j];
  }
  __syncthreads();
  for (int k=0;k<bs;k++){
    double d = 1.0/sm[k*65+k];
    if (tid < bs){ ck[tid] = sm[tid*65+k]; rk[tid] = (tid==k) ? d : sm[k*65+tid]*d; }
    __syncthreads();
    for (int l = tid; l < bs*bs; l += TPB){
      int i=l/bs, j=l-i*bs;
      double v;
      if (i==k) v = rk[j];
      else if (j==k) v = -ck[i]*d;
      else v = sm[i*65+j] - ck[i]*rk[j];
      sm[i*65+j] = v;
    }
    __syncthreads();
  }
  for (int l = tid; l < bs*bs; l += TPB){
    int i=l/bs, j=l-i*bs;
    TP[i*64+j] = sm[i*65+j];
  }
}

__device__ void gj_copies(const double* A, int lda, int n, int k0, int bs,
                          double* TC, double* PR){
  int nout = n - bs;
  int tot = nout*bs;
  for (int l = (blockIdx.x-1)*TPB + threadIdx.x; l < tot; l += (GRID-1)*TPB){
    int rr = l/bs, j = l - rr*bs;
    int i = (rr < k0) ? rr : rr + bs;
    TC[(size_t)rr*64 + j] = A[(size_t)i*lda + k0 + j];
  }
  int tot2 = bs*n;
  for (int l = (blockIdx.x-1)*TPB + threadIdx.x; l < tot2; l += (GRID-1)*TPB){
    int k = l/n, j = l - k*n;
    PR[(size_t)k*PRLD + j] = A[(size_t)(k0+k)*lda + j];
  }
}

// Phase B (fused rowupd+mainupd), round-9 verified incl. pivot-col TP substitution.
__device__ void gj_phaseB(double* A, int lda, int n, int k0, const double* TP,
                          const double* TC, const double* PR, double* shd){
  int bs = n - k0; if (bs > 64) bs = 64;
  int nout = n - bs;
  int ntc = (n+63)>>6, ntm = (nout+63)>>6;
  double* Pn = shd;               // [64][65]
  double* As = shd + 4160;        // [16][66]
  double* Bs = shd + 4160 + 1056; // [16][66]
  int tid = threadIdx.x, tx = tid%16, ty = tid/16;
  int T = ntm*ntc;
  for (int t = blockIdx.x; t < T; t += GRID){
    int mi = t / ntc, ci = t - mi*ntc;
    int m0 = mi*64, j0 = ci*64;
    double acc[4][4] = {};
    for (int kp=0; kp<bs; kp+=16){
      for (int l=tid; l<1024; l+=TPB){
        int k=l>>6, m=l&63;
        As[k*66+m] = (m<bs) ? TP[m*64 + kp+k] : 0.0;
      }
      for (int l=tid; l<1024; l+=TPB){
        int k=l>>6, j=l&63;
        Bs[k*66+j] = (j0+j<n) ? PR[(size_t)(kp+k)*PRLD + j0+j] : 0.0;
      }
      __syncthreads();
      #pragma unroll
      for (int kk=0; kk<16; ++kk){
        double a0=As[kk*66+ty*4+0], a1=As[kk*66+ty*4+1], a2=As[kk*66+ty*4+2], a3=As[kk*66+ty*4+3];
        double b0=Bs[kk*66+tx*4+0], b1=Bs[kk*66+tx*4+1], b2=Bs[kk*66+tx*4+2], b3=Bs[kk*66+tx*4+3];
        acc[0][0]+=a0*b0; acc[0][1]+=a0*b1; acc[0][2]+=a0*b2; acc[0][3]+=a0*b3;
        acc[1][0]+=a1*b0; acc[1][1]+=a1*b1; acc[1][2]+=a1*b2; acc[1][3]+=a1*b3;
        acc[2][0]+=a2*b0; acc[2][1]+=a2*b1; acc[2][2]+=a2*b2; acc[2][3]+=a2*b3;
        acc[3][0]+=a3*b0; acc[3][1]+=a3*b1; acc[3][2]+=a3*b2; acc[3][3]+=a3*b3;
      }
      __syncthreads();
    }
    for (int i=0;i<4;i++) for (int j=0;j<4;j++){
      int li = ty*4+i, lj = tx*4+j;
      int gj = j0 + lj;
      double v = acc[i][j];
      if (gj >= k0 && gj < k0+bs && li < bs) v = TP[li*64 + (gj-k0)];
      Pn[li*65+lj] = v;
    }
    __syncthreads();
    if (mi == 0){
      for (int l = tid; l < 64*64; l += TPB){
        int i2 = l>>6, j2 = l&63;
        int gj = j0 + j2;
        if (i2 < bs && gj < n) A[(size_t)(k0+i2)*lda + gj] = Pn[i2*65+j2];
      }
    }
    double acc2[4][4] = {};
    for (int kp=0; kp<bs; kp+=16){
      for (int l=tid; l<1024; l+=TPB){
        int k=l>>6, m=l&63;
        As[k*66+m] = (m0+m<nout) ? TC[(size_t)(m0+m)*64 + kp+k] : 0.0;
      }
      __syncthreads();
      #pragma unroll
      for (int kk=0; kk<16; ++kk){
        double a0=As[kk*66+ty*4+0], a1=As[kk*66+ty*4+1], a2=As[kk*66+ty*4+2], a3=As[kk*66+ty*4+3];
        double b0=Pn[(kp+kk)*65+tx*4+0], b1=Pn[(kp+kk)*65+tx*4+1],
               b2=Pn[(kp+kk)*65+tx*4+2], b3=Pn[(kp+kk)*65+tx*4+3];
        acc2[0][0]+=a0*b0; acc2[0][1]+=a0*b1; acc2[0][2]+=a0*b2; acc2[0][3]+=a0*b3;
        acc2[1][0]+=a1*b0; acc2[1][1]+=a1*b1; acc2[1][2]+=a1*b2; acc2[1][3]+=a1*b3;
        acc2[2][0]+=a2*b0; acc2[2][1]+=a2*b1; acc2[2][2]+=a2*b2; acc2[2][3]+=a2*b3;
        acc2[3][0]+=a3*b0; acc2[3][1]+=a3*b1; acc2[3][2]+=a3*b2; acc2[3][3]+=a3*b3;
      }
      __syncthreads();
    }
    for (int i=0;i<4;i++) for (int j=0;j<4;j++){
      int gm = m0 + ty*4 + i, gj = j0 + tx*4 + j;
      if (gm < nout && gj < n){
        int gi = (gm < k0) ? gm : gm + bs;
        double base = (gj >= k0 && gj < k0+bs) ? 0.0 : A[(size_t)gi*lda + gj];
        A[(size_t)gi*lda + gj] = base - acc2[i][j];
      }
    }
    __syncthreads();
  }
}

__device__ void gj_inv(double* A, int n, double* TP, double* TC, double* PR,
                       double* shd, unsigned* cnt, int& bid){
  for (int k0 = 0; k0 < n; k0 += 64){
    int bs = n - k0; if (bs > 64) bs = 64;
    if (blockIdx.x == 0) gj_pivinv(A, n, n, k0, TP, shd);
    else gj_copies(A, n, n, k0, bs, TC, PR);
    gbar(cnt, bid);
    gj_phaseB(A, n, n, k0, TP, TC, PR, shd);
    gbar(cnt, bid);
  }
}

// ---------------- misc stages ----------------
__device__ void st_copy(const double* s, double* d, size_t n){
  for (size_t i = (size_t)blockIdx.x*TPB + threadIdx.x; i < n; i += (size_t)gridDim.x*TPB)
    d[i] = s[i];
}

__device__ void st_out(const double* Bg, float* out){
  int stride = gridDim.x*TPB;
  for (int idx = blockIdx.x*TPB + threadIdx.x; idx < 128*800; idx += stride){
    if (idx < 128*320){
      int t = idx/320, i = idx-(idx/320)*320;
      out[idx] = (float)Bg[(size_t)(480+i)*NBT + t];
    } else {
      int l = idx - 128*320;
      int t = l/480, i = l-(l/480)*480;
      out[idx] = (float)Bg[(size_t)i*NBT + t];
    }
  }
}

__global__ __launch_bounds__(256) void k_init(unsigned* cnt){
  int i = blockIdx.x*256 + threadIdx.x;
  if (i < 1024) cnt[i] = 0;
}

// ---------------- mega kernel ----------------
__global__ __launch_bounds__(256) void k_mega(
    const float* Up, const float* Yp, const float* Uf, const float* Yf,
    const float* q, const float* r, const float* lam,
    const float* yref, const float* uref, const float* u_ini, const float* y_ini,
    float* out,
    double* Gram, double* M11, double* T12, double* G1, double* SP, double* R1,
    double* U1, double* X2b, double* Sm, double* dM, double* rhs2, double* tAc,
    double* P1, double* BUZ, double* TP, double* TC, double* PR, unsigned* cnt){
  __shared__ double shd[6272];
  int bid = 0;
  double sg = 2.0*(double)lam[0];
  double isg = 1.0/sg, isg2 = isg*isg;

  st_gram(Yf, Uf, Up, Yp, Gram, shd);
  gbar(cnt, bid);
  st_assemble(Gram, q, r, isg, yref, uref, u_ini, y_ini, M11, T12, R1, dM, rhs2);
  gbar(cnt, bid);
  // {3,14,17}
  dgemm<0,1>(Gram, NQ, dM, NBT, R1+NC, NRHS, R1+NC, NRHS, KU, NBT, KB, 1.0, 0.0, shd);
  dgemm<0,0>(Gram+(size_t)800*NQ, NQ, dM, NBT, rhs2, NBT, tAc, NBT, NC, NBT, KB, isg, 1.0, shd);
  dgemm<0,0>(Gram, NQ, dM, NBT, P1, NBT, P1, NBT, KB, NBT, KB, isg, 0.0, shd);
  gbar(cnt, bid);
  gj_inv(M11, KB, TP, TC, PR, shd, cnt, bid);
  // {5,8}
  dgemm<0,0>(M11, KB, T12, KP, G1, KP, G1, KP, KB, KP, KB, 1.0, 0.0, shd);
  dgemm<0,0>(M11, KB, R1, NRHS, U1, NRHS, U1, NRHS, KB, NRHS, KB, 1.0, 0.0, shd);
  gbar(cnt, bid);
  // {6,9}
  dgemm<1,0>(T12, KP, G1, KP, SP, KP, SP, KP, KP, KP, KB, 1.0, 0.0, shd);
  dgemm<1,0>(T12, KP, U1, NRHS, R1+(size_t)KB*NRHS, NRHS, R1+(size_t)KB*NRHS, NRHS,
             KP, NRHS, KB, 1.0, -1.0, shd);
  gbar(cnt, bid);
  gj_inv(SP, KP, TP, TC, PR, shd, cnt, bid);
  dgemm<0,0>(SP, KP, R1+(size_t)KB*NRHS, NRHS, X2b, NRHS, X2b, NRHS, KP, NRHS, KP, 1.0, 0.0, shd);
  gbar(cnt, bid);
  // {11}
  st_copy(X2b, R1+(size_t)KB*NRHS, (size_t)KP*NRHS);
  dgemm<0,0>(G1, KP, X2b, NRHS, U1, NRHS, R1, NRHS, KB, NRHS, KP, -1.0, 1.0, shd);
  gbar(cnt, bid);
  // {12,15,19,20}
  dgemm<1,1>(Gram+800, NQ, R1, NRHS, Gram+(size_t)800*NQ+800, NQ, Sm, NC,
             NC, NC, KU, -isg2, isg, shd);
  dgemm<1,1>(Gram+800, NQ, R1+NC, NRHS, tAc, NBT, rhs2, NBT, NC, NBT, KU, -isg2, 1.0, shd);
  dgemm<1,1>(Gram, NQ, R1+NC, NRHS, P1, NBT, P1, NBT, KB, NBT, KU, -isg2, 1.0, shd);
  dgemm<1,1>(Gram, NQ, R1, NRHS, BUZ, NC, BUZ, NC, KB, NC, KU, 1.0, 0.0, shd);
  gbar(cnt, bid);
  gj_inv(Sm, NC, TP, TC, PR, shd, cnt, bid);
  dgemm<0,0>(Sm, NC, rhs2, NBT, tAc, NBT, tAc, NBT, NC, NBT, NC, 1.0, 0.0, shd);
  gbar(cnt, bid);
  // {18,21}
  dgemm<0,0>(Gram+800, NQ, tAc, NBT, P1, NBT, P1, NBT, KB, NBT, NC, -isg, 1.0, shd);
  dgemm<0,0>(BUZ, NC, tAc, NBT, P1, NBT, P1, NBT, KB, NBT, NC, isg2, 1.0, shd);
  gbar(cnt, bid);
  st_out(P1, out);
}

extern "C" void kernel_launch(void* const* d_in, const int* in_sizes, int n_in,
                              void* d_out, int out_size, void* d_ws, size_t ws_size,
                              hipStream_t stream){
  const float* Up   = (const float*)d_in[0];
  const float* Yp   = (const float*)d_in[1];
  const float* Uf   = (const float*)d_in[2];
  const float* Yf   = (const float*)d_in[3];
  // d_in[4] = IPI : unused (projector handled analytically)
  const float* q    = (const float*)d_in[5];
  const float* r    = (const float*)d_in[6];
  const float* lam  = (const float*)d_in[7];
  const float* yref = (const float*)d_in[8];
  const float* uref = (const float*)d_in[9];
  const float* u_ini= (const float*)d_in[10];
  const float* y_ini= (const float*)d_in[11];
  float* out = (float*)d_out;

  double* W = (double*)d_ws;
  size_t o = 0;
  double* Gram = W + o; o += (size_t)NQ*NQ;
  double* M11  = W + o; o += (size_t)KB*KB;
  double* T12  = W + o; o += (size_t)KB*KP;
  double* G1   = W + o; o += (size_t)KB*KP;
  double* SP   = W + o; o += (size_t)KP*KP;
  double* R1   = W + o; o += (size_t)KU*NRHS;
  double* U1   = W + o; o += (size_t)KB*NRHS;
  double* X2b  = W + o; o += (size_t)KP*NRHS;
  double* Sm   = W + o; o += (size_t)NC*NC;
  double* dM   = W + o; o += (size_t)KB*NBT;
  double* rhs2 = W + o; o += (size_t)NC*NBT;
  double* tAc  = W + o; o += (size_t)NC*NBT;
  double* P1   = W + o; o += (size_t)KB*NBT;
  double* BUZ  = W + o; o += (size_t)KB*NC;
  double* TP   = W + o; o += (size_t)64*64;
  double* TC   = W + o; o += (size_t)KB*64;
  double* PR   = W + o; o += (size_t)64*PRLD;
  unsigned* cnt = (unsigned*)(W + o); o += 512;
  if (ws_size < o*sizeof(double)) return;

  k_init<<<4,256,0,stream>>>(cnt);
  k_mega<<<GRID,TPB,0,stream>>>(Up,Yp,Uf,Yf,q,r,lam,yref,uref,u_ini,y_ini,out,
      Gram,M11,T12,G1,SP,R1,U1,X2b,Sm,dM,rhs2,tAc,P1,BUZ,TP,TC,PR,cnt);
}